// Round 11
// baseline (432.663 us; speedup 1.0000x reference)
//
#include <hip/hip_runtime.h>
#include <math.h>

#define N_NODES 100000
#define N_EDGES 1000000
#define HID 64
#define OUT_DIM 32
#define NUM_GRAPHS 512
#define CAP 48     // max in-degree; deg ~ Poisson(10), P(any overflow) ~ 1e-13
#define NBUCK 391  // dst >> 8 -> buckets of 256 nodes
#define BCAP 3072  // mean 2560, sd ~51 -> 10 sigma margin
#define ACHUNK 4096

typedef __attribute__((ext_vector_type(4))) float f4v;
typedef __attribute__((ext_vector_type(8))) short s8v;  // 8 bf16 in 4 VGPRs

// fp32 -> bf16 (RNE) and back, as raw shorts
static __device__ inline short f2bf(float f) {
  unsigned u = __float_as_uint(f);
  unsigned r = (u + 0x7fffu + ((u >> 16) & 1u)) >> 16;
  return (short)r;
}
static __device__ inline float bf2f(short s) {
  return __uint_as_float(((unsigned)(unsigned short)s) << 16);
}

// ---------------------------------------------------------------------------
// Prep (1 dispatch): weight hi/lo transpose tables + graph starts + zero
// deg/bcnt. Segments by global thread id.
// ---------------------------------------------------------------------------
__global__ __launch_bounds__(256) void prep_kernel(
    const float* __restrict__ W1a, const float* __restrict__ W2a,
    const float* __restrict__ W1b, const float* __restrict__ W2b,
    short* __restrict__ wtab, const int* __restrict__ batch,
    int* __restrict__ starts, int* __restrict__ deg, int* __restrict__ bcnt) {
  int t = blockIdx.x * 256 + threadIdx.x;
  if (t < 16384) {  // 4 x 64x64 weight prep
    int which = t >> 12;
    int r = t & 4095;
    const float* W = (which == 0) ? W1a : (which == 1) ? W2a : (which == 2) ? W1b : W2b;
    short* hiT = wtab + which * 8192;
    short* loT = hiT + 4096;
    int n = r & 63, k = r >> 6;
    float w = W[k * HID + n];
    short h = f2bf(w);
    hiT[n * HID + k] = h;
    loT[n * HID + k] = f2bf(w - bf2f(h));
  } else if (t < 16384 + NUM_GRAPHS + 1) {  // starts[g] = lower_bound(batch,g)
    int g = t - 16384;
    int lo = 0, hi = N_NODES;
    while (lo < hi) {
      int mid = (lo + hi) >> 1;
      if (batch[mid] < g) lo = mid + 1; else hi = mid;
    }
    starts[g] = lo;
  } else if (t < 16897 + N_NODES) {
    deg[t - 16897] = 0;
  } else if (t < 16897 + N_NODES + NBUCK) {
    bcnt[t - 16897 - N_NODES] = 0;
  }
}

// ---------------------------------------------------------------------------
// CSR build pass A: radix-partition edges into 391 dst-buckets (dst>>8).
// LDS counting-sort per 4096-edge chunk, flush contiguous runs (one cursor
// atomic per bucket per block). Dense appends instead of scattered lines.
// ---------------------------------------------------------------------------
__global__ __launch_bounds__(256) void bucket_kernel(
    const int* __restrict__ ei, int* __restrict__ bedge,
    int* __restrict__ bcnt, int n_edges) {
  __shared__ int s_pack[ACHUNK];
  __shared__ short s_b[ACHUNK];
  __shared__ int s_sorted[ACHUNK];
  __shared__ int s_hist[NBUCK];
  __shared__ int s_off[NBUCK];
  __shared__ int s_base[NBUCK];

  int e0 = blockIdx.x * ACHUNK;
  int n = n_edges - e0;
  if (n > ACHUNK) n = ACHUNK;

  for (int i = threadIdx.x; i < NBUCK; i += 256) s_hist[i] = 0;
  __syncthreads();

  for (int i = threadIdx.x; i < n; i += 256) {
    int src = ei[e0 + i];
    int dst = ei[n_edges + e0 + i];
    int b = dst >> 8;
    s_pack[i] = src | ((dst & 255) << 17);  // src:17b | dstLocal:8b
    s_b[i] = (short)b;
    atomicAdd(&s_hist[b], 1);
  }
  __syncthreads();

  if (threadIdx.x == 0) {  // exclusive scan (tiny, serial)
    int run = 0;
    for (int b = 0; b < NBUCK; b++) { s_off[b] = run; run += s_hist[b]; }
  }
  __syncthreads();
  for (int b = threadIdx.x; b < NBUCK; b += 256) {  // reserve global space
    int c = s_hist[b];
    s_base[b] = c > 0 ? atomicAdd(&bcnt[b], c) : 0;
  }
  __syncthreads();

  for (int i = threadIdx.x; i < n; i += 256) {  // LDS scatter (sort)
    int p = atomicAdd(&s_off[s_b[i]], 1);
    s_sorted[p] = s_pack[i];
  }
  __syncthreads();

  for (int b = 0; b < NBUCK; b++) {  // flush contiguous runs
    int cnt = s_hist[b];
    if (cnt == 0) continue;
    int start = s_off[b] - cnt;  // s_off[b] is now end offset
    int gbase = s_base[b];
    for (int i = threadIdx.x; i < cnt; i += 256) {
      int idx = gbase + i;
      if (idx < BCAP) bedge[b * BCAP + idx] = s_sorted[start + i];
    }
  }
}

// ---------------------------------------------------------------------------
// CSR build pass B: one block per bucket; writes confined to a 48 KB csr
// slice + 1 KB deg slice (L2-resident until done).
// ---------------------------------------------------------------------------
__global__ __launch_bounds__(256) void csr_from_buckets_kernel(
    const int* __restrict__ bedge, const int* __restrict__ bcnt,
    int* __restrict__ deg, int* __restrict__ csr) {
  int b = blockIdx.x;
  int n = bcnt[b];
  if (n > BCAP) n = BCAP;
  for (int i = threadIdx.x; i < n; i += 256) {
    int e = bedge[b * BCAP + i];
    int src = e & 0x1FFFF;
    int dst = (b << 8) | (e >> 17);
    int slot = atomicAdd(&deg[dst], 1);
    if (slot < CAP) csr[dst * CAP + slot] = src;
  }
}

// ---------------------------------------------------------------------------
// FUSED GIN layer: gather neighbors -> LDS (bf16 hi/lo rows) -> MFMA MLP.
//   out = (relu?)( relu((x_i + sum_j x_j) @ W1 + b1) @ W2 + b2 )
// NOTE: x (read) and out (write) MUST be disjoint buffers — the gather phase
// reads random rows of x while other blocks' epilogues write out (R10 bug:
// x==out aliasing corrupted late gathers).
// Block = 4 waves, 64 nodes; wave owns 16 nodes (no cross-wave LDS sharing).
// SHFL DISCIPLINE (R3/R6 lesson): every __shfl is full-wave under uniform
// control (bounds from wave-max degree dm); only loads are predicated.
// ---------------------------------------------------------------------------
#define GLPAD 72  // row stride in shorts (16B-aligned rows)

__global__ __launch_bounds__(256) void gin_fused_kernel(
    const float* __restrict__ x, const int* __restrict__ deg,
    const int* __restrict__ csr,
    const short* __restrict__ W1hi, const short* __restrict__ W1lo,
    const float* __restrict__ b1,
    const short* __restrict__ W2hi, const short* __restrict__ W2lo,
    const float* __restrict__ b2,
    float* __restrict__ out, int n_nodes, int apply_relu) {
  __shared__ short Ghi[64 * GLPAD];  // 9.2 KB
  __shared__ short Glo[64 * GLPAD];  // 9.2 KB

  int lane = threadIdx.x & 63;
  int wv = threadIdx.x >> 6;
  int g = lane >> 4, sub = lane & 15;
  int blockBase = blockIdx.x * 64;
  const f4v* x4 = (const f4v*)x;

  // ---- gather phase: wave wv gathers nodes wv*16 .. wv*16+15 ----
  for (int r = 0; r < 4; r++) {
    int nl = wv * 16 + r * 4 + g;  // node-local 0..63, group g owns one node
    int node = blockBase + nl;
    bool nv = node < n_nodes;
    int nc = nv ? node : 0;
    int d = deg[nc];
    if (!nv) d = 0;
    if (d > CAP) d = CAP;
    int dm = d;                          // wave-max degree (uniform bound)
    dm = max(dm, __shfl_xor(dm, 16));
    dm = max(dm, __shfl_xor(dm, 32));
    f4v a = nv ? x4[(size_t)nc * 16 + sub] : (f4v){0.f, 0.f, 0.f, 0.f};
    f4v a1 = {0.f, 0.f, 0.f, 0.f};
    for (int c = 0; c < dm; c += 16) {   // uniform trip count
      int idx = (c + sub < d) ? csr[nc * CAP + c + sub] : 0;
      int lim = dm - c; if (lim > 16) lim = 16;  // uniform
      int j = 0;
      for (; j + 2 <= lim; j += 2) {
        int sa = __shfl(idx, g * 16 + j);      // full-wave, unconditional
        int sb = __shfl(idx, g * 16 + j + 1);
        if (c + j < d)     a  += x4[(size_t)sa * 16 + sub];  // predicated load
        if (c + j + 1 < d) a1 += x4[(size_t)sb * 16 + sub];
      }
      if (j < lim) {
        int sa = __shfl(idx, g * 16 + j);
        if (c + j < d) a += x4[(size_t)sa * 16 + sub];
      }
    }
    a += a1;
    short* gh = Ghi + nl * GLPAD + 4 * sub;
    short* gl = Glo + nl * GLPAD + 4 * sub;
#pragma unroll
    for (int cc = 0; cc < 4; cc++) {
      float v = a[cc];
      short hb = f2bf(v);
      gh[cc] = hb;
      gl[cc] = f2bf(v - bf2f(hb));
    }
  }
  __syncthreads();  // order gather writes vs A-frag reads (cross-lane)

  // ---- MFMA phase (R7-proven) ----
  int m = lane & 15, quad = lane >> 4;
  int rowBase = wv * 16;

  s8v ahi[2], alo[2];
#pragma unroll
  for (int kb = 0; kb < 2; kb++) {
    int off = (rowBase + m) * GLPAD + kb * 32 + quad * 8;
    ahi[kb] = *(const s8v*)(Ghi + off);
    alo[kb] = *(const s8v*)(Glo + off);
  }

  // matmul 1: H = hbuf @ W1   (4 MFMAs per (kb,nt): hh+hl+lh+ll)
  f4v acc[4];
#pragma unroll
  for (int nt = 0; nt < 4; nt++) acc[nt] = (f4v){0.f, 0.f, 0.f, 0.f};
#pragma unroll
  for (int kb = 0; kb < 2; kb++) {
#pragma unroll
    for (int nt = 0; nt < 4; nt++) {
      int n = nt * 16 + m;
      s8v bh = *(const s8v*)(W1hi + n * HID + kb * 32 + quad * 8);
      s8v bl = *(const s8v*)(W1lo + n * HID + kb * 32 + quad * 8);
      acc[nt] = __builtin_amdgcn_mfma_f32_16x16x32_bf16(ahi[kb], bh, acc[nt], 0, 0, 0);
      acc[nt] = __builtin_amdgcn_mfma_f32_16x16x32_bf16(ahi[kb], bl, acc[nt], 0, 0, 0);
      acc[nt] = __builtin_amdgcn_mfma_f32_16x16x32_bf16(alo[kb], bh, acc[nt], 0, 0, 0);
      acc[nt] = __builtin_amdgcn_mfma_f32_16x16x32_bf16(alo[kb], bl, acc[nt], 0, 0, 0);
    }
  }

  // bias + relu, stage H back into Ghi/Glo (wave-private rows)
#pragma unroll
  for (int nt = 0; nt < 4; nt++) {
    int col = nt * 16 + m;
    float bb = b1[col];
#pragma unroll
    for (int r = 0; r < 4; r++) {
      int row = rowBase + quad * 4 + r;
      float h = fmaxf(acc[nt][r] + bb, 0.f);
      short hb = f2bf(h);
      Ghi[row * GLPAD + col] = hb;
      Glo[row * GLPAD + col] = f2bf(h - bf2f(hb));
    }
  }
  __syncthreads();  // order H writes vs a2 reads (cross-lane)

  s8v a2hi[2], a2lo[2];
#pragma unroll
  for (int kb = 0; kb < 2; kb++) {
    int off = (rowBase + m) * GLPAD + kb * 32 + quad * 8;
    a2hi[kb] = *(const s8v*)(Ghi + off);
    a2lo[kb] = *(const s8v*)(Glo + off);
  }

  // matmul 2: OUT = H @ W2
  f4v acc2[4];
#pragma unroll
  for (int nt = 0; nt < 4; nt++) acc2[nt] = (f4v){0.f, 0.f, 0.f, 0.f};
#pragma unroll
  for (int kb = 0; kb < 2; kb++) {
#pragma unroll
    for (int nt = 0; nt < 4; nt++) {
      int n = nt * 16 + m;
      s8v bh = *(const s8v*)(W2hi + n * HID + kb * 32 + quad * 8);
      s8v bl = *(const s8v*)(W2lo + n * HID + kb * 32 + quad * 8);
      acc2[nt] = __builtin_amdgcn_mfma_f32_16x16x32_bf16(a2hi[kb], bh, acc2[nt], 0, 0, 0);
      acc2[nt] = __builtin_amdgcn_mfma_f32_16x16x32_bf16(a2hi[kb], bl, acc2[nt], 0, 0, 0);
      acc2[nt] = __builtin_amdgcn_mfma_f32_16x16x32_bf16(a2lo[kb], bh, acc2[nt], 0, 0, 0);
      acc2[nt] = __builtin_amdgcn_mfma_f32_16x16x32_bf16(a2lo[kb], bl, acc2[nt], 0, 0, 0);
    }
  }

  // epilogue: bias (+relu), store
#pragma unroll
  for (int nt = 0; nt < 4; nt++) {
    int col = nt * 16 + m;
    float bb = b2[col];
#pragma unroll
    for (int r = 0; r < 4; r++) {
      int row = quad * 4 + r;
      int onode = blockBase + rowBase + row;
      if (onode < n_nodes) {
        float o = acc2[nt][r] + bb;
        if (apply_relu) o = fmaxf(o, 0.f);
        out[(size_t)onode * HID + col] = o;
      }
    }
  }
}

// ---------------------------------------------------------------------------
// Pooling: one wave per graph (batch sorted -> contiguous range). No atomics.
// ---------------------------------------------------------------------------
__global__ __launch_bounds__(256) void pool_kernel(
    const float* __restrict__ emb, const int* __restrict__ starts,
    float* __restrict__ sums) {
  int lane = threadIdx.x & 63;
  int g = blockIdx.x * 4 + (threadIdx.x >> 6);
  int group = lane >> 4, sub = lane & 15;
  int s0 = starts[g], s1 = starts[g + 1];

  const f4v* e4 = (const f4v*)emb;
  f4v acc = {0.f, 0.f, 0.f, 0.f};
  for (int n = s0 + group; n < s1; n += 4) {
    f4v v = e4[(size_t)n * 16 + sub];
    v.x = fmaxf(v.x, 0.f); v.y = fmaxf(v.y, 0.f);
    v.z = fmaxf(v.z, 0.f); v.w = fmaxf(v.w, 0.f);
    acc += v;
  }
  acc.x += __shfl_xor(acc.x, 16); acc.y += __shfl_xor(acc.y, 16);
  acc.z += __shfl_xor(acc.z, 16); acc.w += __shfl_xor(acc.w, 16);
  acc.x += __shfl_xor(acc.x, 32); acc.y += __shfl_xor(acc.y, 32);
  acc.z += __shfl_xor(acc.z, 32); acc.w += __shfl_xor(acc.w, 32);
  if (lane < 16) ((f4v*)sums)[g * 16 + sub] = acc;
}

// ---------------------------------------------------------------------------
// Head: pooled = sums/max(cnt,1); o = (pooled@Wp1+bp1)@Wp2+bp2; log_softmax.
// ---------------------------------------------------------------------------
__global__ __launch_bounds__(64) void head_kernel(
    const float* __restrict__ sums, const int* __restrict__ starts,
    const float* __restrict__ Wp1, const float* __restrict__ bp1,
    const float* __restrict__ Wp2, const float* __restrict__ bp2,
    float* __restrict__ out) {
  int g = blockIdx.x;
  int lane = threadIdx.x;
  float c = fmaxf((float)(starts[g + 1] - starts[g]), 1.0f);
  float p = sums[g * HID + lane] / c;

  float t = bp1[lane];
#pragma unroll
  for (int k = 0; k < HID; k++) {
    t += __shfl(p, k) * Wp1[k * HID + lane];
  }

  float acc = 0.0f;
#pragma unroll
  for (int k = 0; k < HID; k++) {
    float tk = __shfl(t, k);
    if (lane < OUT_DIM) acc += tk * Wp2[k * OUT_DIM + lane];
  }
  float o = (lane < OUT_DIM) ? (acc + bp2[lane]) : -1e30f;

  float m = o;
#pragma unroll
  for (int off = 32; off >= 1; off >>= 1) m = fmaxf(m, __shfl_xor(m, off));
  float ex = (lane < OUT_DIM) ? expf(o - m) : 0.0f;
  float s = ex;
#pragma unroll
  for (int off = 32; off >= 1; off >>= 1) s += __shfl_xor(s, off);
  float lse = m + logf(s);
  if (lane < OUT_DIM) out[g * OUT_DIM + lane] = o - lse;
}

extern "C" void kernel_launch(void* const* d_in, const int* in_sizes, int n_in,
                              void* d_out, int out_size, void* d_ws, size_t ws_size,
                              hipStream_t stream) {
  const float* x   = (const float*)d_in[0];
  const int* ei    = (const int*)d_in[1];
  const int* batch = (const int*)d_in[2];
  const float* W1a = (const float*)d_in[3];
  const float* b1a = (const float*)d_in[4];
  const float* W2a = (const float*)d_in[5];
  const float* b2a = (const float*)d_in[6];
  const float* W1b = (const float*)d_in[7];
  const float* b1b = (const float*)d_in[8];
  const float* W2b = (const float*)d_in[9];
  const float* b2b = (const float*)d_in[10];
  const float* Wp1 = (const float*)d_in[11];
  const float* bp1 = (const float*)d_in[12];
  const float* Wp2 = (const float*)d_in[13];
  const float* bp2 = (const float*)d_in[14];

  float* emb    = (float*)d_out;                          // [N_NODES, HID]
  float* logits = (float*)d_out + (size_t)N_NODES * HID;  // [NUM_GRAPHS, OUT_DIM]

  // ws: x1 [N*HID f32, first 4.8MB doubles as bedge] | bcnt | deg | csr |
  //     starts | sums | wtab   (~45.4 MB, R9-proven scale)
  // x1 is a SEPARATE buffer from emb: the fused kernel must never read and
  // write the same array (R10 race).
  float* x1    = (float*)d_ws;
  int* bedge   = (int*)d_ws;                       // alias: dead before layer 0
  int* bcnt    = (int*)(x1 + (size_t)N_NODES * HID);
  int* deg     = bcnt + NBUCK;
  int* csr     = deg + N_NODES;
  int* starts  = csr + (size_t)N_NODES * CAP;
  float* sums  = (float*)(starts + NUM_GRAPHS + 1);
  short* wtab  = (short*)(sums + NUM_GRAPHS * HID);
  short* W1aHi = wtab + 0 * 4096; short* W1aLo = wtab + 1 * 4096;
  short* W2aHi = wtab + 2 * 4096; short* W2aLo = wtab + 3 * 4096;
  short* W1bHi = wtab + 4 * 4096; short* W1bLo = wtab + 5 * 4096;
  short* W2bHi = wtab + 6 * 4096; short* W2bLo = wtab + 7 * 4096;

  // ----- prep: weights + starts + zero deg/bcnt (1 dispatch) -----
  int prep_threads = 16384 + (NUM_GRAPHS + 1) + N_NODES + NBUCK;
  prep_kernel<<<(prep_threads + 255) / 256, 256, 0, stream>>>(
      W1a, W2a, W1b, W2b, wtab, batch, starts, deg, bcnt);

  // ----- inverse adjacency: radix-bucketed 2-pass build -----
  bucket_kernel<<<(N_EDGES + ACHUNK - 1) / ACHUNK, 256, 0, stream>>>(
      ei, bedge, bcnt, N_EDGES);
  csr_from_buckets_kernel<<<NBUCK, 256, 0, stream>>>(bedge, bcnt, deg, csr);

  int fused_blocks = (N_NODES + 63) / 64;

  // ----- layer 0: x1 = relu(MLP_a(x + agg(x)))   [reads x, writes x1] -----
  gin_fused_kernel<<<fused_blocks, 256, 0, stream>>>(
      x, deg, csr, W1aHi, W1aLo, b1a, W2aHi, W2aLo, b2a, x1, N_NODES, 1);

  // ----- layer 1: emb = MLP_b(x1 + agg(x1))      [reads x1, writes emb] ----
  gin_fused_kernel<<<fused_blocks, 256, 0, stream>>>(
      x1, deg, csr, W1bHi, W1bLo, b1b, W2bHi, W2bLo, b2b, emb, N_NODES, 0);

  // ----- pooling + head -----
  pool_kernel<<<NUM_GRAPHS / 4, 256, 0, stream>>>(emb, starts, sums);
  head_kernel<<<NUM_GRAPHS, 64, 0, stream>>>(sums, starts, Wp1, bp1, Wp2, bp2, logits);
}

// Round 12
// 360.715 us; speedup vs baseline: 1.1995x; 1.1995x over previous
//
#include <hip/hip_runtime.h>
#include <math.h>

#define N_NODES 100000
#define N_EDGES 1000000
#define HID 64
#define OUT_DIM 32
#define NUM_GRAPHS 512
#define CAP 48      // max in-degree; deg ~ Poisson(10), P(any overflow) ~ 1e-13
#define NBUCK 98    // dst >> 10 -> buckets of 1024 nodes (R9-proven)
#define BCAP 11264  // bucket capacity; mean 10204 -> 10+ sigma margin
#define ACHUNK 4096

typedef __attribute__((ext_vector_type(4))) float f4v;
typedef __attribute__((ext_vector_type(8))) short s8v;  // 8 bf16 in 4 VGPRs

// fp32 -> bf16 (RNE) and back, as raw shorts
static __device__ inline short f2bf(float f) {
  unsigned u = __float_as_uint(f);
  unsigned r = (u + 0x7fffu + ((u >> 16) & 1u)) >> 16;
  return (short)r;
}
static __device__ inline float bf2f(short s) {
  return __uint_as_float(((unsigned)(unsigned short)s) << 16);
}

// ---------------------------------------------------------------------------
// Prep (1 dispatch): weight hi/lo transpose tables + graph starts + zero
// deg/bcnt. Segments by global thread id. (R11-proven)
// ---------------------------------------------------------------------------
__global__ __launch_bounds__(256) void prep_kernel(
    const float* __restrict__ W1a, const float* __restrict__ W2a,
    const float* __restrict__ W1b, const float* __restrict__ W2b,
    short* __restrict__ wtab, const int* __restrict__ batch,
    int* __restrict__ starts, int* __restrict__ deg, int* __restrict__ bcnt) {
  int t = blockIdx.x * 256 + threadIdx.x;
  if (t < 16384) {  // 4 x 64x64 weight prep
    int which = t >> 12;
    int r = t & 4095;
    const float* W = (which == 0) ? W1a : (which == 1) ? W2a : (which == 2) ? W1b : W2b;
    short* hiT = wtab + which * 8192;
    short* loT = hiT + 4096;
    int n = r & 63, k = r >> 6;
    float w = W[k * HID + n];
    short h = f2bf(w);
    hiT[n * HID + k] = h;
    loT[n * HID + k] = f2bf(w - bf2f(h));
  } else if (t < 16384 + NUM_GRAPHS + 1) {  // starts[g] = lower_bound(batch,g)
    int g = t - 16384;
    int lo = 0, hi = N_NODES;
    while (lo < hi) {
      int mid = (lo + hi) >> 1;
      if (batch[mid] < g) lo = mid + 1; else hi = mid;
    }
    starts[g] = lo;
  } else if (t < 16897 + N_NODES) {
    deg[t - 16897] = 0;
  } else if (t < 16897 + N_NODES + NBUCK) {
    bcnt[t - 16897 - N_NODES] = 0;
  }
}

// ---------------------------------------------------------------------------
// CSR build pass A (R9-proven, NBUCK=98): radix-partition edges into
// dst-buckets; LDS counting-sort per 4096-edge chunk, flush contiguous runs.
// ---------------------------------------------------------------------------
__global__ __launch_bounds__(256) void bucket_kernel(
    const int* __restrict__ ei, int* __restrict__ bedge,
    int* __restrict__ bcnt, int n_edges) {
  __shared__ int s_pack[ACHUNK];
  __shared__ unsigned char s_b[ACHUNK];
  __shared__ int s_sorted[ACHUNK];
  __shared__ int s_hist[NBUCK];
  __shared__ int s_off[NBUCK];
  __shared__ int s_base[NBUCK];

  int e0 = blockIdx.x * ACHUNK;
  int n = n_edges - e0;
  if (n > ACHUNK) n = ACHUNK;

  for (int i = threadIdx.x; i < NBUCK; i += 256) s_hist[i] = 0;
  __syncthreads();

  for (int i = threadIdx.x; i < n; i += 256) {
    int src = ei[e0 + i];
    int dst = ei[n_edges + e0 + i];
    int b = dst >> 10;
    s_pack[i] = src | ((dst & 1023) << 17);  // src:17b | dstLocal:10b
    s_b[i] = (unsigned char)b;
    atomicAdd(&s_hist[b], 1);
  }
  __syncthreads();

  if (threadIdx.x == 0) {  // exclusive scan over 98 buckets (tiny, serial)
    int run = 0;
    for (int b = 0; b < NBUCK; b++) { s_off[b] = run; run += s_hist[b]; }
  }
  if (threadIdx.x < NBUCK) {  // reserve global space per bucket
    int c = s_hist[threadIdx.x];
    s_base[threadIdx.x] = c > 0 ? atomicAdd(&bcnt[threadIdx.x], c) : 0;
  }
  __syncthreads();

  for (int i = threadIdx.x; i < n; i += 256) {  // LDS scatter (sort)
    int p = atomicAdd(&s_off[s_b[i]], 1);
    s_sorted[p] = s_pack[i];
  }
  __syncthreads();

  for (int b = 0; b < NBUCK; b++) {  // flush contiguous runs
    int cnt = s_hist[b];
    if (cnt == 0) continue;
    int start = s_off[b] - cnt;  // s_off[b] is now end offset
    int gbase = s_base[b];
    for (int i = threadIdx.x; i < cnt; i += 256) {
      int idx = gbase + i;
      if (idx < BCAP) bedge[b * BCAP + idx] = s_sorted[start + i];
    }
  }
}

// ---------------------------------------------------------------------------
// CSR build pass B (R9-proven): one block per bucket; writes confined to a
// 197 KB csr slice + 4 KB deg slice (L2-resident until done).
// ---------------------------------------------------------------------------
__global__ __launch_bounds__(256) void csr_from_buckets_kernel(
    const int* __restrict__ bedge, const int* __restrict__ bcnt,
    int* __restrict__ deg, int* __restrict__ csr) {
  int b = blockIdx.x;
  int n = bcnt[b];
  if (n > BCAP) n = BCAP;
  for (int i = threadIdx.x; i < n; i += 256) {
    int e = bedge[b * BCAP + i];
    int src = e & 0x1FFFF;
    int dst = (b << 10) | (e >> 17);
    int slot = atomicAdd(&deg[dst], 1);
    if (slot < CAP) csr[dst * CAP + slot] = src;
  }
}

// ---------------------------------------------------------------------------
// Gather (R9-proven, 46-49 µs @ 70% occupancy): hbuf[i] = x[i] + sum_j x[j].
// One wave per node; 4 groups x f4v slices, 2 streams/group -> 8 loads in
// flight. SHFL DISCIPLINE: every __shfl full-wave under uniform control;
// only loads predicated. DO NOT fuse with the MLP (R11: occupancy collapse).
// ---------------------------------------------------------------------------
__global__ __launch_bounds__(256) void gather_kernel(
    const float* __restrict__ x, const int* __restrict__ deg,
    const int* __restrict__ csr, float* __restrict__ hbuf, int n_nodes) {
  int lane = threadIdx.x & 63;
  int node = blockIdx.x * (blockDim.x >> 6) + (threadIdx.x >> 6);
  if (node >= n_nodes) return;  // node uniform per wave -> whole wave exits
  int g = lane >> 4;
  int sub = lane & 15;

  int d = deg[node];
  if (d > CAP) d = CAP;
  int idx = (lane < d) ? csr[node * CAP + lane] : 0;

  const f4v* x4 = (const f4v*)x;
  f4v a0 = (g == 0) ? x4[(size_t)node * 16 + sub] : (f4v){0.f, 0.f, 0.f, 0.f};
  f4v a1 = {0.f, 0.f, 0.f, 0.f};
  for (int j0 = 0; j0 < d; j0 += 8) {  // d uniform: all lanes iterate together
    int ja = j0 + g;
    int jb = j0 + 4 + g;
    int sa = __shfl(idx, ja);  // full-wave, unconditional
    int sb = __shfl(idx, jb);
    if (ja < d) a0 += x4[(size_t)sa * 16 + sub];  // predicated load only
    if (jb < d) a1 += x4[(size_t)sb * 16 + sub];
  }
  f4v a = a0 + a1;
  a.x += __shfl_xor(a.x, 16); a.y += __shfl_xor(a.y, 16);
  a.z += __shfl_xor(a.z, 16); a.w += __shfl_xor(a.w, 16);
  a.x += __shfl_xor(a.x, 32); a.y += __shfl_xor(a.y, 32);
  a.z += __shfl_xor(a.z, 32); a.w += __shfl_xor(a.w, 32);
  if (g == 0) ((f4v*)hbuf)[(size_t)node * 16 + sub] = a;
}

// ---------------------------------------------------------------------------
// GIN MLP via MFMA (bf16 hi/lo split, fp32 accumulate). R7/R9-proven.
// ---------------------------------------------------------------------------
#define LPAD 72  // LDS row stride in shorts

__global__ __launch_bounds__(256) void gin_mlp_mfma_kernel(
    const float* __restrict__ hbuf,
    const short* __restrict__ W1hi, const short* __restrict__ W1lo,
    const float* __restrict__ b1,
    const short* __restrict__ W2hi, const short* __restrict__ W2lo,
    const float* __restrict__ b2,
    float* __restrict__ out, int n_nodes, int apply_relu) {
  __shared__ short lds[4][2][16 * LPAD];

  int lane = threadIdx.x & 63;
  int wv = threadIdx.x >> 6;
  int m = lane & 15;
  int quad = lane >> 4;
  int nodeBase = blockIdx.x * 64 + wv * 16;
  int node = nodeBase + m;
  bool valid = node < n_nodes;

  s8v ahi[2], alo[2];
  for (int kb = 0; kb < 2; kb++) {
    int ks = kb * 32 + quad * 8;
    f4v r0 = {0.f, 0.f, 0.f, 0.f}, r1 = {0.f, 0.f, 0.f, 0.f};
    if (valid) {
      const f4v* hp = (const f4v*)(hbuf + (size_t)node * HID + ks);
      r0 = hp[0];
      r1 = hp[1];
    }
    s8v h, l;
#pragma unroll
    for (int j = 0; j < 8; j++) {
      float v = (j < 4) ? r0[j] : r1[j - 4];
      short hb = f2bf(v);
      h[j] = hb;
      l[j] = f2bf(v - bf2f(hb));
    }
    ahi[kb] = h;
    alo[kb] = l;
  }

  f4v acc[4];
#pragma unroll
  for (int nt = 0; nt < 4; nt++) acc[nt] = (f4v){0.f, 0.f, 0.f, 0.f};
#pragma unroll
  for (int kb = 0; kb < 2; kb++) {
#pragma unroll
    for (int nt = 0; nt < 4; nt++) {
      int n = nt * 16 + m;
      s8v bh = *(const s8v*)(W1hi + n * HID + kb * 32 + quad * 8);
      s8v bl = *(const s8v*)(W1lo + n * HID + kb * 32 + quad * 8);
      acc[nt] = __builtin_amdgcn_mfma_f32_16x16x32_bf16(ahi[kb], bh, acc[nt], 0, 0, 0);
      acc[nt] = __builtin_amdgcn_mfma_f32_16x16x32_bf16(ahi[kb], bl, acc[nt], 0, 0, 0);
      acc[nt] = __builtin_amdgcn_mfma_f32_16x16x32_bf16(alo[kb], bh, acc[nt], 0, 0, 0);
      acc[nt] = __builtin_amdgcn_mfma_f32_16x16x32_bf16(alo[kb], bl, acc[nt], 0, 0, 0);
    }
  }

  short* Lhi = lds[wv][0];
  short* Llo = lds[wv][1];
#pragma unroll
  for (int nt = 0; nt < 4; nt++) {
    int col = nt * 16 + m;
    float bb = b1[col];
#pragma unroll
    for (int r = 0; r < 4; r++) {
      int row = quad * 4 + r;
      float h = fmaxf(acc[nt][r] + bb, 0.f);
      short hb = f2bf(h);
      Lhi[row * LPAD + col] = hb;
      Llo[row * LPAD + col] = f2bf(h - bf2f(hb));
    }
  }
  __syncthreads();

  s8v a2hi[2], a2lo[2];
#pragma unroll
  for (int kb = 0; kb < 2; kb++) {
    int off = m * LPAD + kb * 32 + quad * 8;
    a2hi[kb] = *(const s8v*)(Lhi + off);
    a2lo[kb] = *(const s8v*)(Llo + off);
  }

  f4v acc2[4];
#pragma unroll
  for (int nt = 0; nt < 4; nt++) acc2[nt] = (f4v){0.f, 0.f, 0.f, 0.f};
#pragma unroll
  for (int kb = 0; kb < 2; kb++) {
#pragma unroll
    for (int nt = 0; nt < 4; nt++) {
      int n = nt * 16 + m;
      s8v bh = *(const s8v*)(W2hi + n * HID + kb * 32 + quad * 8);
      s8v bl = *(const s8v*)(W2lo + n * HID + kb * 32 + quad * 8);
      acc2[nt] = __builtin_amdgcn_mfma_f32_16x16x32_bf16(a2hi[kb], bh, acc2[nt], 0, 0, 0);
      acc2[nt] = __builtin_amdgcn_mfma_f32_16x16x32_bf16(a2hi[kb], bl, acc2[nt], 0, 0, 0);
      acc2[nt] = __builtin_amdgcn_mfma_f32_16x16x32_bf16(a2lo[kb], bh, acc2[nt], 0, 0, 0);
      acc2[nt] = __builtin_amdgcn_mfma_f32_16x16x32_bf16(a2lo[kb], bl, acc2[nt], 0, 0, 0);
    }
  }

#pragma unroll
  for (int nt = 0; nt < 4; nt++) {
    int col = nt * 16 + m;
    float bb = b2[col];
#pragma unroll
    for (int r = 0; r < 4; r++) {
      int row = quad * 4 + r;
      int onode = nodeBase + row;
      if (onode < n_nodes) {
        float o = acc2[nt][r] + bb;
        if (apply_relu) o = fmaxf(o, 0.f);
        out[(size_t)onode * HID + col] = o;
      }
    }
  }
}

// ---------------------------------------------------------------------------
// Fused pool + head: one wave per graph (4 graphs per 256-block).
// Pool: register f4v run over the graph's contiguous node range (relu'd),
// xor-reduce; redistribute so lane l holds dim l (full-wave shfls, uniform
// control); then head math + log-softmax. No sums buffer, no extra dispatch.
// ---------------------------------------------------------------------------
__global__ __launch_bounds__(256) void poolhead_kernel(
    const float* __restrict__ emb, const int* __restrict__ starts,
    const float* __restrict__ Wp1, const float* __restrict__ bp1,
    const float* __restrict__ Wp2, const float* __restrict__ bp2,
    float* __restrict__ out) {
  int lane = threadIdx.x & 63;
  int g = blockIdx.x * 4 + (threadIdx.x >> 6);  // 512 waves total
  int group = lane >> 4, sub = lane & 15;
  int s0 = starts[g], s1 = starts[g + 1];

  const f4v* e4 = (const f4v*)emb;
  f4v acc = {0.f, 0.f, 0.f, 0.f};
  for (int n = s0 + group; n < s1; n += 4) {
    f4v v = e4[(size_t)n * 16 + sub];
    v.x = fmaxf(v.x, 0.f); v.y = fmaxf(v.y, 0.f);
    v.z = fmaxf(v.z, 0.f); v.w = fmaxf(v.w, 0.f);
    acc += v;
  }
  acc.x += __shfl_xor(acc.x, 16); acc.y += __shfl_xor(acc.y, 16);
  acc.z += __shfl_xor(acc.z, 16); acc.w += __shfl_xor(acc.w, 16);
  acc.x += __shfl_xor(acc.x, 32); acc.y += __shfl_xor(acc.y, 32);
  acc.z += __shfl_xor(acc.z, 32); acc.w += __shfl_xor(acc.w, 32);
  // every lane l now holds the full sum for dims [4*(l&15), 4*(l&15)+3].
  // redistribute: lane l wants dim l -> source lane l>>2, component l&3.
  int srcl = lane >> 2;
  float v0 = __shfl(acc.x, srcl);
  float v1 = __shfl(acc.y, srcl);
  float v2 = __shfl(acc.z, srcl);
  float v3 = __shfl(acc.w, srcl);
  int r = lane & 3;
  float psum = (r == 0) ? v0 : (r == 1) ? v1 : (r == 2) ? v2 : v3;

  float c = fmaxf((float)(s1 - s0), 1.0f);
  float p = psum / c;

  float t = bp1[lane];
#pragma unroll
  for (int k = 0; k < HID; k++) {
    t += __shfl(p, k) * Wp1[k * HID + lane];
  }

  float acc2 = 0.0f;
#pragma unroll
  for (int k = 0; k < HID; k++) {
    float tk = __shfl(t, k);
    if (lane < OUT_DIM) acc2 += tk * Wp2[k * OUT_DIM + lane];
  }
  float o = (lane < OUT_DIM) ? (acc2 + bp2[lane]) : -1e30f;

  float m = o;
#pragma unroll
  for (int off = 32; off >= 1; off >>= 1) m = fmaxf(m, __shfl_xor(m, off));
  float ex = (lane < OUT_DIM) ? expf(o - m) : 0.0f;
  float s = ex;
#pragma unroll
  for (int off = 32; off >= 1; off >>= 1) s += __shfl_xor(s, off);
  float lse = m + logf(s);
  if (lane < OUT_DIM) out[g * OUT_DIM + lane] = o - lse;
}

extern "C" void kernel_launch(void* const* d_in, const int* in_sizes, int n_in,
                              void* d_out, int out_size, void* d_ws, size_t ws_size,
                              hipStream_t stream) {
  const float* x   = (const float*)d_in[0];
  const int* ei    = (const int*)d_in[1];
  const int* batch = (const int*)d_in[2];
  const float* W1a = (const float*)d_in[3];
  const float* b1a = (const float*)d_in[4];
  const float* W2a = (const float*)d_in[5];
  const float* b2a = (const float*)d_in[6];
  const float* W1b = (const float*)d_in[7];
  const float* b1b = (const float*)d_in[8];
  const float* W2b = (const float*)d_in[9];
  const float* b2b = (const float*)d_in[10];
  const float* Wp1 = (const float*)d_in[11];
  const float* bp1 = (const float*)d_in[12];
  const float* Wp2 = (const float*)d_in[13];
  const float* bp2 = (const float*)d_in[14];

  float* emb    = (float*)d_out;                          // [N_NODES, HID]
  float* logits = (float*)d_out + (size_t)N_NODES * HID;  // [NUM_GRAPHS, OUT_DIM]
  // x1 (relu'd layer-0 output) aliases emb: safe because gather and MLP are
  // SEPARATE dispatches (R9-proven). gather1 reads x1 -> hbuf; mlp1 reads
  // hbuf -> writes emb. No dispatch both reads and writes the region.
  float* x1 = emb;

  // ws: hbuf [N*HID f32, first 4.4MB doubles as bedge+bcnt] | deg | csr |
  //     starts | wtab   (~45.3 MB, R9-proven layout)
  float* hbuf  = (float*)d_ws;
  int* bedge   = (int*)d_ws;            // alias: dead before first gather
  int* bcnt    = bedge + NBUCK * BCAP;  // still inside hbuf
  int* deg     = (int*)(hbuf + (size_t)N_NODES * HID);
  int* csr     = deg + N_NODES;
  int* starts  = csr + (size_t)N_NODES * CAP;
  short* wtab  = (short*)(starts + NUM_GRAPHS + 1);
  short* W1aHi = wtab + 0 * 4096; short* W1aLo = wtab + 1 * 4096;
  short* W2aHi = wtab + 2 * 4096; short* W2aLo = wtab + 3 * 4096;
  short* W1bHi = wtab + 4 * 4096; short* W1bLo = wtab + 5 * 4096;
  short* W2bHi = wtab + 6 * 4096; short* W2bLo = wtab + 7 * 4096;

  // ----- prep: weights + starts + zero deg/bcnt (1 dispatch) -----
  int prep_threads = 16384 + (NUM_GRAPHS + 1) + N_NODES + NBUCK;
  prep_kernel<<<(prep_threads + 255) / 256, 256, 0, stream>>>(
      W1a, W2a, W1b, W2b, wtab, batch, starts, deg, bcnt);

  // ----- inverse adjacency: radix-bucketed 2-pass build (R9-proven) -----
  bucket_kernel<<<(N_EDGES + ACHUNK - 1) / ACHUNK, 256, 0, stream>>>(
      ei, bedge, bcnt, N_EDGES);
  csr_from_buckets_kernel<<<NBUCK, 256, 0, stream>>>(bedge, bcnt, deg, csr);

  int gather_blocks = (N_NODES + 3) / 4;  // 4 waves (nodes) per block
  int mlp_blocks = (N_NODES + 63) / 64;

  // ----- layer 0: hbuf = x + agg(x); x1 = relu(MLP_a(hbuf)) -----
  gather_kernel<<<gather_blocks, 256, 0, stream>>>(x, deg, csr, hbuf, N_NODES);
  gin_mlp_mfma_kernel<<<mlp_blocks, 256, 0, stream>>>(
      hbuf, W1aHi, W1aLo, b1a, W2aHi, W2aLo, b2a, x1, N_NODES, /*relu=*/1);

  // ----- layer 1: hbuf = x1 + agg(x1); emb = MLP_b(hbuf) (pre-ReLU) -----
  gather_kernel<<<gather_blocks, 256, 0, stream>>>(x1, deg, csr, hbuf, N_NODES);
  gin_mlp_mfma_kernel<<<mlp_blocks, 256, 0, stream>>>(
      hbuf, W1bHi, W1bLo, b1b, W2bHi, W2bLo, b2b, emb, N_NODES, /*relu=*/0);

  // ----- fused pooling + head (1 dispatch) -----
  poolhead_kernel<<<NUM_GRAPHS / 4, 256, 0, stream>>>(
      emb, starts, Wp1, bp1, Wp2, bp2, logits);
}